// Round 2
// baseline (729.475 us; speedup 1.0000x reference)
//
#include <hip/hip_runtime.h>
#include <math.h>

// Problem constants (fixed by the reference)
constexpr int N    = 50000;
constexpr int E    = 1600000;
constexpr int FD   = 128;   // feature dim (in and out of both GAT layers)
constexpr int H    = 4;     // heads
constexpr int G    = 64;    // graphs
constexpr int NCH  = 16;    // node-chunks per graph for parallel reductions
constexpr int OUT  = 10;

#define DEV __device__ __forceinline__

DEV void fma4(float4& a, float s, const float4& w) {
    a.x = fmaf(s, w.x, a.x); a.y = fmaf(s, w.y, a.y);
    a.z = fmaf(s, w.z, a.z); a.w = fmaf(s, w.w, a.w);
}

DEV float lrelu_exp(float z) {             // exp(leaky_relu(z, 0.2))
    return __expf(z > 0.f ? z : 0.2f * z);
}

// ---------------- setup kernels ----------------

__global__ void k_zero(int* __restrict__ deg, float* __restrict__ hg) {
    int i = blockIdx.x * 256 + threadIdx.x;
    if (i < N) deg[i] = 0;
    if (i < G * FD) hg[i] = 0.f;
}

__global__ void k_graph_starts(const int* __restrict__ batch, int* __restrict__ gs) {
    int i = blockIdx.x * 256 + threadIdx.x;
    if (i >= N) return;
    int b  = batch[i];
    int pb = (i == 0) ? -1 : batch[i - 1];
    for (int g = pb + 1; g <= b; ++g) gs[g] = i;
    if (i == N - 1) for (int g = b + 1; g <= G; ++g) gs[g] = N;
}

__global__ void k_count(const int* __restrict__ dst, int* __restrict__ deg) {
    int e = blockIdx.x * 256 + threadIdx.x;
    if (e < E) atomicAdd(&deg[dst[e]], 1);
}

__global__ void k_scan1(const int* __restrict__ deg, int* __restrict__ exc,
                        int* __restrict__ bsum) {
    __shared__ int sh[256];
    int t = threadIdx.x;
    int i = blockIdx.x * 256 + t;
    int v = (i < N) ? deg[i] : 0;
    sh[t] = v;
    __syncthreads();
    for (int d = 1; d < 256; d <<= 1) {
        int add = (t >= d) ? sh[t - d] : 0;
        __syncthreads();
        sh[t] += add;
        __syncthreads();
    }
    if (i < N) exc[i] = sh[t] - v;           // exclusive within block
    if (t == 255) bsum[blockIdx.x] = sh[255];
}

__global__ void k_scan2(int* __restrict__ bsum, int nb) {
    __shared__ int sh[256];
    int t = threadIdx.x;
    int v = (t < nb) ? bsum[t] : 0;
    sh[t] = v;
    __syncthreads();
    for (int d = 1; d < 256; d <<= 1) {
        int add = (t >= d) ? sh[t - d] : 0;
        __syncthreads();
        sh[t] += add;
        __syncthreads();
    }
    if (t < nb) bsum[t] = sh[t];             // inclusive
}

__global__ void k_scan3(const int* __restrict__ exc, const int* __restrict__ bsum,
                        int* __restrict__ off, int* __restrict__ cursor) {
    int i = blockIdx.x * 256 + threadIdx.x;
    if (i >= N) return;
    int b = i >> 8;
    int base = (b > 0) ? bsum[b - 1] : 0;
    int v = exc[i] + base;
    off[i] = v;
    cursor[i] = v;
    if (i == 0) off[N] = E;
}

__global__ void k_scatter(const int* __restrict__ src, const int* __restrict__ dst,
                          int* __restrict__ cursor, int* __restrict__ col) {
    int e = blockIdx.x * 256 + threadIdx.x;
    if (e < E) {
        int p = atomicAdd(&cursor[dst[e]], 1);
        col[p] = src[e];
    }
}

// ---------------- GEMM + attention-logit epilogue ----------------
// Block: 256 threads; tile = 128 rows x 128 cols; thread = 16 rows x 4 cols.
__global__ __launch_bounds__(256, 2)
void k_gemm_al(const float* __restrict__ X, const float* __restrict__ W,
               const float* __restrict__ a_s, const float* __restrict__ a_d,
               float* __restrict__ hw, float* __restrict__ als, float* __restrict__ ald)
{
    __shared__ float xs[128][128];
    int r0 = blockIdx.x * 128;
    int t  = threadIdx.x;

    // stage 128x128 x-tile (zero-fill out-of-range rows)
    for (int i = 0; i < 16; ++i) {
        int f   = i * 256 + t;          // float4 index
        int row = f >> 5;               // f*4/128
        int colf = (f & 31) * 4;
        float4 v = make_float4(0.f, 0.f, 0.f, 0.f);
        if (r0 + row < N) v = *(const float4*)(X + (size_t)(r0 + row) * FD + colf);
        *(float4*)(&xs[row][colf]) = v;
    }
    __syncthreads();

    int ct = t & 31;        // col-thread 0..31
    int rt = t >> 5;        // row-thread 0..7
    int c4 = ct * 4;
    int rb = rt * 16;

    float4 acc[16];
#pragma unroll
    for (int r = 0; r < 16; ++r) acc[r] = make_float4(0.f, 0.f, 0.f, 0.f);

    for (int k = 0; k < FD; k += 4) {
        float4 wv0 = *(const float4*)(W + (size_t)(k + 0) * FD + c4);
        float4 wv1 = *(const float4*)(W + (size_t)(k + 1) * FD + c4);
        float4 wv2 = *(const float4*)(W + (size_t)(k + 2) * FD + c4);
        float4 wv3 = *(const float4*)(W + (size_t)(k + 3) * FD + c4);
#pragma unroll
        for (int r = 0; r < 16; ++r) {
            float4 xv = *(const float4*)(&xs[rb + r][k]);
            fma4(acc[r], xv.x, wv0);
            fma4(acc[r], xv.y, wv1);
            fma4(acc[r], xv.z, wv2);
            fma4(acc[r], xv.w, wv3);
        }
    }

    int h  = c4 >> 5;
    int j0 = c4 & 31;
    float as0 = a_s[h * 32 + j0 + 0], as1 = a_s[h * 32 + j0 + 1];
    float as2 = a_s[h * 32 + j0 + 2], as3 = a_s[h * 32 + j0 + 3];
    float ad0 = a_d[h * 32 + j0 + 0], ad1 = a_d[h * 32 + j0 + 1];
    float ad2 = a_d[h * 32 + j0 + 2], ad3 = a_d[h * 32 + j0 + 3];

#pragma unroll
    for (int r = 0; r < 16; ++r) {
        int row = r0 + rb + r;
        bool valid = row < N;
        if (valid) *(float4*)(hw + (size_t)row * FD + c4) = acc[r];
        float ps = acc[r].x * as0 + acc[r].y * as1 + acc[r].z * as2 + acc[r].w * as3;
        float pd = acc[r].x * ad0 + acc[r].y * ad1 + acc[r].z * ad2 + acc[r].w * ad3;
        // sum over the 8 consecutive lanes covering this head's 32 cols
#pragma unroll
        for (int m = 1; m < 8; m <<= 1) {
            ps += __shfl_xor(ps, m, 64);
            pd += __shfl_xor(pd, m, 64);
        }
        if ((ct & 7) == 0 && valid) {
            als[row * H + h] = ps;
            ald[row * H + h] = pd;
        }
    }
}

// ---------------- fused edge softmax + aggregation (one wave per dst node) ----------------
// Edge loop unrolled x4 with batched index loads so 4 independent gathers are
// in flight per iteration (latency-bound loop -> 4x memory-level parallelism).
__global__ __launch_bounds__(256)
void k_agg(const float* __restrict__ hw, const float* __restrict__ als,
           const float* __restrict__ ald, const int* __restrict__ off,
           const int* __restrict__ col, const float* __restrict__ bias,
           float* __restrict__ h1)
{
    int n = blockIdx.x * 4 + (threadIdx.x >> 6);
    if (n >= N) return;
    int l = threadIdx.x & 63;
    int h = l >> 4;                 // lane owns cols {2l, 2l+1}; head = 2l/32
    float adn = ald[n * H + h];
    float asn = als[n * H + h];

    // self-loop
    float w = lrelu_exp(asn + adn);
    float2 hv = *(const float2*)(hw + (size_t)n * FD + 2 * l);
    float accx = w * hv.x, accy = w * hv.y, sumw = w;

    int ib = off[n], ie = off[n + 1];
    int i = ib;
    for (; i + 4 <= ie; i += 4) {
        int s0 = col[i + 0];
        int s1 = col[i + 1];
        int s2 = col[i + 2];
        int s3 = col[i + 3];
        float z0 = als[s0 * H + h];
        float z1 = als[s1 * H + h];
        float z2 = als[s2 * H + h];
        float z3 = als[s3 * H + h];
        float2 v0 = *(const float2*)(hw + (size_t)s0 * FD + 2 * l);
        float2 v1 = *(const float2*)(hw + (size_t)s1 * FD + 2 * l);
        float2 v2 = *(const float2*)(hw + (size_t)s2 * FD + 2 * l);
        float2 v3 = *(const float2*)(hw + (size_t)s3 * FD + 2 * l);
        float w0 = lrelu_exp(z0 + adn);
        float w1 = lrelu_exp(z1 + adn);
        float w2 = lrelu_exp(z2 + adn);
        float w3 = lrelu_exp(z3 + adn);
        accx = fmaf(w0, v0.x, accx); accy = fmaf(w0, v0.y, accy);
        accx = fmaf(w1, v1.x, accx); accy = fmaf(w1, v1.y, accy);
        accx = fmaf(w2, v2.x, accx); accy = fmaf(w2, v2.y, accy);
        accx = fmaf(w3, v3.x, accx); accy = fmaf(w3, v3.y, accy);
        sumw += w0 + w1 + w2 + w3;
    }
    for (; i < ie; ++i) {
        int s = col[i];
        float ww = lrelu_exp(als[s * H + h] + adn);
        float2 hv2 = *(const float2*)(hw + (size_t)s * FD + 2 * l);
        accx = fmaf(ww, hv2.x, accx);
        accy = fmaf(ww, hv2.y, accy);
        sumw += ww;
    }
    float inv = 1.f / sumw;
    float ox = fmaf(accx, inv, bias[2 * l]);
    float oy = fmaf(accy, inv, bias[2 * l + 1]);
    ox = ox > 0.f ? ox : 0.f;     // fused ReLU
    oy = oy > 0.f ? oy : 0.f;
    float2 o = make_float2(ox, oy);
    *(float2*)(h1 + (size_t)n * FD + 2 * l) = o;
}

// ---------------- per-graph column softmax stats (chunked) ----------------
__global__ void k_colstats_part(const float* __restrict__ h1, const int* __restrict__ gs,
                                float* __restrict__ Mp, float* __restrict__ Sp)
{
    int g = blockIdx.x, ch = blockIdx.y, c = threadIdx.x;   // 128 threads
    int s = gs[g], e = gs[g + 1];
    int per = (e - s + NCH - 1) / NCH;
    int ns = s + ch * per;
    int ne = min(ns + per, e);
    float m = -3e38f;
    for (int n = ns; n < ne; ++n) m = fmaxf(m, h1[(size_t)n * FD + c]);
    float sum = 0.f;
    for (int n = ns; n < ne; ++n) sum += __expf(h1[(size_t)n * FD + c] - m);
    int o = (g * NCH + ch) * FD + c;
    Mp[o] = m; Sp[o] = sum;
}

__global__ void k_colstats_comb(const float* __restrict__ Mp, const float* __restrict__ Sp,
                                float* __restrict__ Mm, float* __restrict__ Sinv)
{
    int g = blockIdx.x, c = threadIdx.x;
    float m = -3e38f;
#pragma unroll
    for (int ch = 0; ch < NCH; ++ch) m = fmaxf(m, Mp[(g * NCH + ch) * FD + c]);
    float s = 0.f;
#pragma unroll
    for (int ch = 0; ch < NCH; ++ch) {
        float sp = Sp[(g * NCH + ch) * FD + c];
        if (sp > 0.f) s += sp * __expf(Mp[(g * NCH + ch) * FD + c] - m);
    }
    Mm[g * FD + c] = m;
    Sinv[g * FD + c] = 1.f / s;
}

// ---------------- node softmax-normalize + gate logits ----------------
__global__ __launch_bounds__(256)
void k_softmax_gate(const float* __restrict__ h1, const int* __restrict__ batch,
                    const float* __restrict__ Mm, const float* __restrict__ Sinv,
                    const float* __restrict__ gw, const float* __restrict__ gb,
                    float* __restrict__ hsm, float* __restrict__ gl)
{
    int n = blockIdx.x * 4 + (threadIdx.x >> 6);
    if (n >= N) return;
    int l = threadIdx.x & 63;
    int g = batch[n];
    float2 hv = *(const float2*)(h1 + (size_t)n * FD + 2 * l);
    float2 mv = *(const float2*)(Mm + g * FD + 2 * l);
    float2 sv = *(const float2*)(Sinv + g * FD + 2 * l);
    float vx = __expf(hv.x - mv.x) * sv.x;
    float vy = __expf(hv.y - mv.y) * sv.y;
    float2 o = make_float2(vx, vy);
    *(float2*)(hsm + (size_t)n * FD + 2 * l) = o;
    float p = vx * gw[2 * l] + vy * gw[2 * l + 1];
#pragma unroll
    for (int m = 1; m < 64; m <<= 1) p += __shfl_xor(p, m, 64);
    if (l == 0) gl[n] = p + gb[0];
}

// ---------------- per-graph gate softmax stats ----------------
__global__ __launch_bounds__(256)
void k_gatestats(const float* __restrict__ gl, const int* __restrict__ gs,
                 float* __restrict__ Mg, float* __restrict__ iSg)
{
    __shared__ float red[8];
    int g = blockIdx.x;
    int s = gs[g], e = gs[g + 1];
    int t = threadIdx.x;
    float m = -3e38f;
    for (int i = s + t; i < e; i += 256) m = fmaxf(m, gl[i]);
#pragma unroll
    for (int mk = 1; mk < 64; mk <<= 1) m = fmaxf(m, __shfl_xor(m, mk, 64));
    if ((t & 63) == 0) red[t >> 6] = m;
    __syncthreads();
    if (t == 0) {
        float mm = red[0];
        for (int w2 = 1; w2 < 4; ++w2) mm = fmaxf(mm, red[w2]);
        red[0] = mm;
    }
    __syncthreads();
    m = red[0];
    float sum = 0.f;
    for (int i = s + t; i < e; i += 256) sum += __expf(gl[i] - m);
#pragma unroll
    for (int mk = 1; mk < 64; mk <<= 1) sum += __shfl_xor(sum, mk, 64);
    if ((t & 63) == 0) red[4 + (t >> 6)] = sum;
    __syncthreads();
    if (t == 0) {
        float ss = red[4] + red[5] + red[6] + red[7];
        Mg[g] = m;
        iSg[g] = 1.f / ss;
    }
}

// ---------------- gated pooling (chunked, atomic accumulate into hg) ----------------
__global__ void k_pool(const float* __restrict__ hsm, const float* __restrict__ gl,
                       const int* __restrict__ gs, const float* __restrict__ Mg,
                       const float* __restrict__ iSg, float* __restrict__ hg)
{
    int g = blockIdx.x, ch = blockIdx.y, c = threadIdx.x;
    int s = gs[g], e = gs[g + 1];
    int per = (e - s + NCH - 1) / NCH;
    int ns = s + ch * per;
    int ne = min(ns + per, e);
    float mg = Mg[g], is = iSg[g];
    float acc = 0.f;
    for (int n = ns; n < ne; ++n)
        acc = fmaf(__expf(gl[n] - mg) * is, hsm[(size_t)n * FD + c], acc);
    atomicAdd(&hg[g * FD + c], acc);
}

// ---------------- final MLP head ----------------
__global__ __launch_bounds__(64)
void k_head(const float* __restrict__ hg, const float* __restrict__ lin_w,
            const float* __restrict__ lin_b, const float* __restrict__ cls_w,
            const float* __restrict__ cls_b, float* __restrict__ out)
{
    __shared__ float hrow[128];
    __shared__ float tbuf[64];
    int g = blockIdx.x, j = threadIdx.x;
    hrow[j]      = hg[g * FD + j];
    hrow[j + 64] = hg[g * FD + j + 64];
    __syncthreads();
    float a = lin_b[j];
    for (int c = 0; c < 128; ++c) a = fmaf(hrow[c], lin_w[c * 64 + j], a);
    tbuf[j] = a > 0.f ? a : 0.f;
    __syncthreads();
    if (j < OUT) {
        float o = cls_b[j];
        for (int k = 0; k < 64; ++k) o = fmaf(tbuf[k], cls_w[k * OUT + j], o);
        out[g * OUT + j] = o;
    }
}

// ---------------- host launcher ----------------
extern "C" void kernel_launch(void* const* d_in, const int* in_sizes, int n_in,
                              void* d_out, int out_size, void* d_ws, size_t ws_size,
                              hipStream_t stream)
{
    const float* x      = (const float*)d_in[0];
    const int*   ei     = (const int*)d_in[1];
    const int*   src    = ei;
    const int*   dst    = ei + E;
    const int*   batch  = (const int*)d_in[2];
    const float* W1     = (const float*)d_in[3];
    const float* as1    = (const float*)d_in[4];
    const float* ad1    = (const float*)d_in[5];
    const float* b1     = (const float*)d_in[6];
    const float* W2     = (const float*)d_in[7];
    const float* as2    = (const float*)d_in[8];
    const float* ad2    = (const float*)d_in[9];
    const float* b2     = (const float*)d_in[10];
    const float* gate_w = (const float*)d_in[11];
    const float* gate_b = (const float*)d_in[12];
    const float* lin_w  = (const float*)d_in[13];
    const float* lin_b  = (const float*)d_in[14];
    const float* cls_w  = (const float*)d_in[15];
    const float* cls_b  = (const float*)d_in[16];
    float* outp = (float*)d_out;

    char* ws = (char*)d_ws;
    size_t o = 0;
    auto alloc = [&](size_t bytes) -> char* {
        char* p = ws + o;
        o = (o + bytes + 255) & ~(size_t)255;
        return p;
    };

    int*   gs     = (int*)alloc((G + 1) * sizeof(int));
    int*   deg    = (int*)alloc(N * sizeof(int));
    int*   exc    = (int*)alloc(N * sizeof(int));
    int*   bsum   = (int*)alloc(256 * sizeof(int));
    int*   off    = (int*)alloc((N + 1) * sizeof(int));
    int*   cursor = (int*)alloc(N * sizeof(int));
    int*   col    = (int*)alloc((size_t)E * sizeof(int));
    float* als    = (float*)alloc((size_t)N * H * sizeof(float));
    float* ald    = (float*)alloc((size_t)N * H * sizeof(float));
    float* hw     = (float*)alloc((size_t)N * FD * sizeof(float));
    float* h1     = (float*)alloc((size_t)N * FD * sizeof(float));
    float* hsm    = (float*)alloc((size_t)N * FD * sizeof(float));
    float* Mp     = (float*)alloc((size_t)G * NCH * FD * sizeof(float));
    float* Sp     = (float*)alloc((size_t)G * NCH * FD * sizeof(float));
    float* Mm     = (float*)alloc((size_t)G * FD * sizeof(float));
    float* Sinv   = (float*)alloc((size_t)G * FD * sizeof(float));
    float* gl     = (float*)alloc((size_t)N * sizeof(float));
    float* Mg     = (float*)alloc(G * sizeof(float));
    float* iSg    = (float*)alloc(G * sizeof(float));
    float* hg     = (float*)alloc((size_t)G * FD * sizeof(float));

    int nbN = (N + 255) / 256;
    int nbE = (E + 255) / 256;

    // CSR build + zero init
    k_zero<<<nbN, 256, 0, stream>>>(deg, hg);
    k_graph_starts<<<nbN, 256, 0, stream>>>(batch, gs);
    k_count<<<nbE, 256, 0, stream>>>(dst, deg);
    k_scan1<<<nbN, 256, 0, stream>>>(deg, exc, bsum);
    k_scan2<<<1, 256, 0, stream>>>(bsum, nbN);
    k_scan3<<<nbN, 256, 0, stream>>>(exc, bsum, off, cursor);
    k_scatter<<<nbE, 256, 0, stream>>>(src, dst, cursor, col);

    auto run_layer = [&](const float* hin, const float* W, const float* a_s,
                         const float* a_d, const float* bias) {
        k_gemm_al<<<(N + 127) / 128, 256, 0, stream>>>(hin, W, a_s, a_d, hw, als, ald);
        k_agg<<<(N + 3) / 4, 256, 0, stream>>>(hw, als, ald, off, col, bias, h1);
        k_colstats_part<<<dim3(G, NCH), 128, 0, stream>>>(h1, gs, Mp, Sp);
        k_colstats_comb<<<G, 128, 0, stream>>>(Mp, Sp, Mm, Sinv);
        k_softmax_gate<<<(N + 3) / 4, 256, 0, stream>>>(h1, batch, Mm, Sinv, gate_w, gate_b, hsm, gl);
        k_gatestats<<<G, 256, 0, stream>>>(gl, gs, Mg, iSg);
        k_pool<<<dim3(G, NCH), 128, 0, stream>>>(hsm, gl, gs, Mg, iSg, hg);
    };

    run_layer(x, W1, as1, ad1, b1);
    run_layer(hsm, W2, as2, ad2, b2);

    k_head<<<G, 64, 0, stream>>>(hg, lin_w, lin_b, cls_w, cls_b, outp);
}

// Round 3
// 578.311 us; speedup vs baseline: 1.2614x; 1.2614x over previous
//
#include <hip/hip_runtime.h>
#include <math.h>

// Problem constants (fixed by the reference)
constexpr int N    = 50000;
constexpr int E    = 1600000;
constexpr int FD   = 128;   // feature dim (in and out of both GAT layers)
constexpr int H    = 4;     // heads
constexpr int G    = 64;    // graphs
constexpr int NCH  = 16;    // node-chunks per graph for parallel reductions
constexpr int OUT  = 10;

// CSR-build partition parameters
constexpr int NBIN   = (N + 255) / 256;        // 196 bins of 256 nodes (bin = dst>>8)
constexpr int EPB    = 4096;                   // edges per partition block
constexpr int NBLK_E = (E + EPB - 1) / EPB;    // 391

#define DEV __device__ __forceinline__

DEV void fma4(float4& a, float s, const float4& w) {
    a.x = fmaf(s, w.x, a.x); a.y = fmaf(s, w.y, a.y);
    a.z = fmaf(s, w.z, a.z); a.w = fmaf(s, w.w, a.w);
}

DEV float lrelu_exp(float z) {             // exp(leaky_relu(z, 0.2))
    return __expf(z > 0.f ? z : 0.2f * z);
}

// ---------------- setup kernels ----------------

__global__ void k_zero(int* __restrict__ hist, float* __restrict__ hg) {
    int i = blockIdx.x * 256 + threadIdx.x;
    if (i < NBIN) hist[i] = 0;
    if (i < G * FD) hg[i] = 0.f;
}

__global__ void k_graph_starts(const int* __restrict__ batch, int* __restrict__ gs) {
    int i = blockIdx.x * 256 + threadIdx.x;
    if (i >= N) return;
    int b  = batch[i];
    int pb = (i == 0) ? -1 : batch[i - 1];
    for (int g = pb + 1; g <= b; ++g) gs[g] = i;
    if (i == N - 1) for (int g = b + 1; g <= G; ++g) gs[g] = N;
}

// Coarse histogram: 196 bins, LDS-aggregated (196 global atomics per block).
__global__ __launch_bounds__(256)
void k_hist(const int* __restrict__ dst, int* __restrict__ hist) {
    __shared__ int lh[NBIN];
    int t = threadIdx.x;
    for (int i = t; i < NBIN; i += 256) lh[i] = 0;
    __syncthreads();
    int base = blockIdx.x * EPB;
#pragma unroll
    for (int j = 0; j < EPB / 256; ++j) {
        int e = base + j * 256 + t;
        if (e < E) atomicAdd(&lh[dst[e] >> 8], 1);
    }
    __syncthreads();
    for (int i = t; i < NBIN; i += 256) if (lh[i]) atomicAdd(&hist[i], lh[i]);
}

// Scan bin totals -> bin bases + partition cursors; also off[N]=E.
__global__ __launch_bounds__(256)
void k_binscan(const int* __restrict__ hist, int* __restrict__ binbase,
               int* __restrict__ cursor, int* __restrict__ off) {
    __shared__ int sh[256];
    int t = threadIdx.x;
    int v = (t < NBIN) ? hist[t] : 0;
    sh[t] = v;
    __syncthreads();
    for (int d = 1; d < 256; d <<= 1) {
        int add = (t >= d) ? sh[t - d] : 0;
        __syncthreads();
        sh[t] += add;
        __syncthreads();
    }
    if (t < NBIN) {
        binbase[t] = sh[t] - v;       // exclusive
        cursor[t]  = sh[t] - v;
    }
    if (t == NBIN - 1) binbase[NBIN] = sh[t];   // == E
    if (t == 0) off[N] = E;
}

// Partition edges into bin-contiguous storage. Pack: src (16b) | dstLocal (8b) << 16.
// Per-(block,bin) runs are contiguous (one reservation atomic per bin per block),
// so line sharing happens only at run boundaries -> no 16x write amplification.
__global__ __launch_bounds__(256)
void k_partition(const int* __restrict__ src, const int* __restrict__ dst,
                 int* __restrict__ cursor, unsigned int* __restrict__ part) {
    __shared__ int lh[NBIN];
    __shared__ int gb[NBIN];
    int t = threadIdx.x;
    for (int i = t; i < NBIN; i += 256) lh[i] = 0;
    __syncthreads();
    int base = blockIdx.x * EPB;
    unsigned int pk[EPB / 256];
    int          pr[EPB / 256];        // (bin<<16) | rank, or -1
#pragma unroll
    for (int j = 0; j < EPB / 256; ++j) {
        int e = base + j * 256 + t;
        if (e < E) {
            int d = dst[e];
            int b = d >> 8;
            int r = atomicAdd(&lh[b], 1);            // local rank within (block,bin)
            pk[j] = (unsigned)src[e] | ((unsigned)(d & 255) << 16);
            pr[j] = (b << 16) | r;
        } else pr[j] = -1;
    }
    __syncthreads();
    for (int i = t; i < NBIN; i += 256) gb[i] = atomicAdd(&cursor[i], lh[i]);
    __syncthreads();
#pragma unroll
    for (int j = 0; j < EPB / 256; ++j) {
        if (pr[j] >= 0) {
            int b = pr[j] >> 16, r = pr[j] & 0xFFFF;
            part[gb[b] + r] = pk[j];
        }
    }
}

// Fine pass: one block per bin. LDS histogram over the bin's 256 nodes ->
// per-node CSR offsets (off[]) + scatter src into the bin's contiguous col
// region (L2-resident, single-block-owned -> single writeback per line).
__global__ __launch_bounds__(256)
void k_fine(const unsigned int* __restrict__ part, const int* __restrict__ binbase,
            int* __restrict__ off, int* __restrict__ col) {
    __shared__ int lh[256], lo[256], lc[256];
    int b = blockIdx.x, t = threadIdx.x;
    int s = binbase[b], e = binbase[b + 1];
    lh[t] = 0; lc[t] = 0;
    __syncthreads();
    for (int i = s + t; i < e; i += 256) atomicAdd(&lh[part[i] >> 16], 1);
    __syncthreads();
    int v = lh[t];
    lo[t] = v;
    __syncthreads();
    for (int d = 1; d < 256; d <<= 1) {
        int add = (t >= d) ? lo[t - d] : 0;
        __syncthreads();
        lo[t] += add;
        __syncthreads();
    }
    int ex = lo[t] - v;                 // exclusive scan
    __syncthreads();
    lo[t] = ex;
    __syncthreads();
    int node = b * 256 + t;
    if (node < N) off[node] = s + ex;
    for (int i = s + t; i < e; i += 256) {
        unsigned p = part[i];
        int dl = p >> 16;
        int r = atomicAdd(&lc[dl], 1);
        col[s + lo[dl] + r] = (int)(p & 0xFFFFu);
    }
}

// ---------------- GEMM + attention-logit epilogue ----------------
// Block: 256 threads; tile = 128 rows x 128 cols; thread = 16 rows x 4 cols.
__global__ __launch_bounds__(256, 2)
void k_gemm_al(const float* __restrict__ X, const float* __restrict__ W,
               const float* __restrict__ a_s, const float* __restrict__ a_d,
               float* __restrict__ hw, float* __restrict__ als, float* __restrict__ ald)
{
    __shared__ float xs[128][128];
    int r0 = blockIdx.x * 128;
    int t  = threadIdx.x;

    for (int i = 0; i < 16; ++i) {
        int f   = i * 256 + t;
        int row = f >> 5;
        int colf = (f & 31) * 4;
        float4 v = make_float4(0.f, 0.f, 0.f, 0.f);
        if (r0 + row < N) v = *(const float4*)(X + (size_t)(r0 + row) * FD + colf);
        *(float4*)(&xs[row][colf]) = v;
    }
    __syncthreads();

    int ct = t & 31;
    int rt = t >> 5;
    int c4 = ct * 4;
    int rb = rt * 16;

    float4 acc[16];
#pragma unroll
    for (int r = 0; r < 16; ++r) acc[r] = make_float4(0.f, 0.f, 0.f, 0.f);

    for (int k = 0; k < FD; k += 4) {
        float4 wv0 = *(const float4*)(W + (size_t)(k + 0) * FD + c4);
        float4 wv1 = *(const float4*)(W + (size_t)(k + 1) * FD + c4);
        float4 wv2 = *(const float4*)(W + (size_t)(k + 2) * FD + c4);
        float4 wv3 = *(const float4*)(W + (size_t)(k + 3) * FD + c4);
#pragma unroll
        for (int r = 0; r < 16; ++r) {
            float4 xv = *(const float4*)(&xs[rb + r][k]);
            fma4(acc[r], xv.x, wv0);
            fma4(acc[r], xv.y, wv1);
            fma4(acc[r], xv.z, wv2);
            fma4(acc[r], xv.w, wv3);
        }
    }

    int h  = c4 >> 5;
    int j0 = c4 & 31;
    float as0 = a_s[h * 32 + j0 + 0], as1 = a_s[h * 32 + j0 + 1];
    float as2 = a_s[h * 32 + j0 + 2], as3 = a_s[h * 32 + j0 + 3];
    float ad0 = a_d[h * 32 + j0 + 0], ad1 = a_d[h * 32 + j0 + 1];
    float ad2 = a_d[h * 32 + j0 + 2], ad3 = a_d[h * 32 + j0 + 3];

#pragma unroll
    for (int r = 0; r < 16; ++r) {
        int row = r0 + rb + r;
        bool valid = row < N;
        if (valid) *(float4*)(hw + (size_t)row * FD + c4) = acc[r];
        float ps = acc[r].x * as0 + acc[r].y * as1 + acc[r].z * as2 + acc[r].w * as3;
        float pd = acc[r].x * ad0 + acc[r].y * ad1 + acc[r].z * ad2 + acc[r].w * ad3;
#pragma unroll
        for (int m = 1; m < 8; m <<= 1) {
            ps += __shfl_xor(ps, m, 64);
            pd += __shfl_xor(pd, m, 64);
        }
        if ((ct & 7) == 0 && valid) {
            als[row * H + h] = ps;
            ald[row * H + h] = pd;
        }
    }
}

// ---------------- fused edge softmax + aggregation (one wave per dst node) ----------------
__global__ __launch_bounds__(256)
void k_agg(const float* __restrict__ hw, const float* __restrict__ als,
           const float* __restrict__ ald, const int* __restrict__ off,
           const int* __restrict__ col, const float* __restrict__ bias,
           float* __restrict__ h1)
{
    int n = blockIdx.x * 4 + (threadIdx.x >> 6);
    if (n >= N) return;
    int l = threadIdx.x & 63;
    int h = l >> 4;
    float adn = ald[n * H + h];
    float asn = als[n * H + h];

    float w = lrelu_exp(asn + adn);
    float2 hv = *(const float2*)(hw + (size_t)n * FD + 2 * l);
    float accx = w * hv.x, accy = w * hv.y, sumw = w;

    int ib = off[n], ie = off[n + 1];
    int i = ib;
    for (; i + 4 <= ie; i += 4) {
        int s0 = col[i + 0];
        int s1 = col[i + 1];
        int s2 = col[i + 2];
        int s3 = col[i + 3];
        float z0 = als[s0 * H + h];
        float z1 = als[s1 * H + h];
        float z2 = als[s2 * H + h];
        float z3 = als[s3 * H + h];
        float2 v0 = *(const float2*)(hw + (size_t)s0 * FD + 2 * l);
        float2 v1 = *(const float2*)(hw + (size_t)s1 * FD + 2 * l);
        float2 v2 = *(const float2*)(hw + (size_t)s2 * FD + 2 * l);
        float2 v3 = *(const float2*)(hw + (size_t)s3 * FD + 2 * l);
        float w0 = lrelu_exp(z0 + adn);
        float w1 = lrelu_exp(z1 + adn);
        float w2 = lrelu_exp(z2 + adn);
        float w3 = lrelu_exp(z3 + adn);
        accx = fmaf(w0, v0.x, accx); accy = fmaf(w0, v0.y, accy);
        accx = fmaf(w1, v1.x, accx); accy = fmaf(w1, v1.y, accy);
        accx = fmaf(w2, v2.x, accx); accy = fmaf(w2, v2.y, accy);
        accx = fmaf(w3, v3.x, accx); accy = fmaf(w3, v3.y, accy);
        sumw += w0 + w1 + w2 + w3;
    }
    for (; i < ie; ++i) {
        int s = col[i];
        float ww = lrelu_exp(als[s * H + h] + adn);
        float2 hv2 = *(const float2*)(hw + (size_t)s * FD + 2 * l);
        accx = fmaf(ww, hv2.x, accx);
        accy = fmaf(ww, hv2.y, accy);
        sumw += ww;
    }
    float inv = 1.f / sumw;
    float ox = fmaf(accx, inv, bias[2 * l]);
    float oy = fmaf(accy, inv, bias[2 * l + 1]);
    ox = ox > 0.f ? ox : 0.f;
    oy = oy > 0.f ? oy : 0.f;
    float2 o = make_float2(ox, oy);
    *(float2*)(h1 + (size_t)n * FD + 2 * l) = o;
}

// ---------------- per-graph column softmax stats (chunked) ----------------
__global__ void k_colstats_part(const float* __restrict__ h1, const int* __restrict__ gs,
                                float* __restrict__ Mp, float* __restrict__ Sp)
{
    int g = blockIdx.x, ch = blockIdx.y, c = threadIdx.x;
    int s = gs[g], e = gs[g + 1];
    int per = (e - s + NCH - 1) / NCH;
    int ns = s + ch * per;
    int ne = min(ns + per, e);
    float m = -3e38f;
    for (int n = ns; n < ne; ++n) m = fmaxf(m, h1[(size_t)n * FD + c]);
    float sum = 0.f;
    for (int n = ns; n < ne; ++n) sum += __expf(h1[(size_t)n * FD + c] - m);
    int o = (g * NCH + ch) * FD + c;
    Mp[o] = m; Sp[o] = sum;
}

__global__ void k_colstats_comb(const float* __restrict__ Mp, const float* __restrict__ Sp,
                                float* __restrict__ Mm, float* __restrict__ Sinv)
{
    int g = blockIdx.x, c = threadIdx.x;
    float m = -3e38f;
#pragma unroll
    for (int ch = 0; ch < NCH; ++ch) m = fmaxf(m, Mp[(g * NCH + ch) * FD + c]);
    float s = 0.f;
#pragma unroll
    for (int ch = 0; ch < NCH; ++ch) {
        float sp = Sp[(g * NCH + ch) * FD + c];
        if (sp > 0.f) s += sp * __expf(Mp[(g * NCH + ch) * FD + c] - m);
    }
    Mm[g * FD + c] = m;
    Sinv[g * FD + c] = 1.f / s;
}

// ---------------- node softmax-normalize + gate logits ----------------
__global__ __launch_bounds__(256)
void k_softmax_gate(const float* __restrict__ h1, const int* __restrict__ batch,
                    const float* __restrict__ Mm, const float* __restrict__ Sinv,
                    const float* __restrict__ gw, const float* __restrict__ gb,
                    float* __restrict__ hsm, float* __restrict__ gl)
{
    int n = blockIdx.x * 4 + (threadIdx.x >> 6);
    if (n >= N) return;
    int l = threadIdx.x & 63;
    int g = batch[n];
    float2 hv = *(const float2*)(h1 + (size_t)n * FD + 2 * l);
    float2 mv = *(const float2*)(Mm + g * FD + 2 * l);
    float2 sv = *(const float2*)(Sinv + g * FD + 2 * l);
    float vx = __expf(hv.x - mv.x) * sv.x;
    float vy = __expf(hv.y - mv.y) * sv.y;
    float2 o = make_float2(vx, vy);
    *(float2*)(hsm + (size_t)n * FD + 2 * l) = o;
    float p = vx * gw[2 * l] + vy * gw[2 * l + 1];
#pragma unroll
    for (int m = 1; m < 64; m <<= 1) p += __shfl_xor(p, m, 64);
    if (l == 0) gl[n] = p + gb[0];
}

// ---------------- per-graph gate softmax stats ----------------
__global__ __launch_bounds__(256)
void k_gatestats(const float* __restrict__ gl, const int* __restrict__ gs,
                 float* __restrict__ Mg, float* __restrict__ iSg)
{
    __shared__ float red[8];
    int g = blockIdx.x;
    int s = gs[g], e = gs[g + 1];
    int t = threadIdx.x;
    float m = -3e38f;
    for (int i = s + t; i < e; i += 256) m = fmaxf(m, gl[i]);
#pragma unroll
    for (int mk = 1; mk < 64; mk <<= 1) m = fmaxf(m, __shfl_xor(m, mk, 64));
    if ((t & 63) == 0) red[t >> 6] = m;
    __syncthreads();
    if (t == 0) {
        float mm = red[0];
        for (int w2 = 1; w2 < 4; ++w2) mm = fmaxf(mm, red[w2]);
        red[0] = mm;
    }
    __syncthreads();
    m = red[0];
    float sum = 0.f;
    for (int i = s + t; i < e; i += 256) sum += __expf(gl[i] - m);
#pragma unroll
    for (int mk = 1; mk < 64; mk <<= 1) sum += __shfl_xor(sum, mk, 64);
    if ((t & 63) == 0) red[4 + (t >> 6)] = sum;
    __syncthreads();
    if (t == 0) {
        float ss = red[4] + red[5] + red[6] + red[7];
        Mg[g] = m;
        iSg[g] = 1.f / ss;
    }
}

// ---------------- gated pooling (chunked, atomic accumulate into hg) ----------------
__global__ void k_pool(const float* __restrict__ hsm, const float* __restrict__ gl,
                       const int* __restrict__ gs, const float* __restrict__ Mg,
                       const float* __restrict__ iSg, float* __restrict__ hg)
{
    int g = blockIdx.x, ch = blockIdx.y, c = threadIdx.x;
    int s = gs[g], e = gs[g + 1];
    int per = (e - s + NCH - 1) / NCH;
    int ns = s + ch * per;
    int ne = min(ns + per, e);
    float mg = Mg[g], is = iSg[g];
    float acc = 0.f;
    for (int n = ns; n < ne; ++n)
        acc = fmaf(__expf(gl[n] - mg) * is, hsm[(size_t)n * FD + c], acc);
    atomicAdd(&hg[g * FD + c], acc);
}

// ---------------- final MLP head ----------------
__global__ __launch_bounds__(64)
void k_head(const float* __restrict__ hg, const float* __restrict__ lin_w,
            const float* __restrict__ lin_b, const float* __restrict__ cls_w,
            const float* __restrict__ cls_b, float* __restrict__ out)
{
    __shared__ float hrow[128];
    __shared__ float tbuf[64];
    int g = blockIdx.x, j = threadIdx.x;
    hrow[j]      = hg[g * FD + j];
    hrow[j + 64] = hg[g * FD + j + 64];
    __syncthreads();
    float a = lin_b[j];
    for (int c = 0; c < 128; ++c) a = fmaf(hrow[c], lin_w[c * 64 + j], a);
    tbuf[j] = a > 0.f ? a : 0.f;
    __syncthreads();
    if (j < OUT) {
        float o = cls_b[j];
        for (int k = 0; k < 64; ++k) o = fmaf(tbuf[k], cls_w[k * OUT + j], o);
        out[g * OUT + j] = o;
    }
}

// ---------------- host launcher ----------------
extern "C" void kernel_launch(void* const* d_in, const int* in_sizes, int n_in,
                              void* d_out, int out_size, void* d_ws, size_t ws_size,
                              hipStream_t stream)
{
    const float* x      = (const float*)d_in[0];
    const int*   ei     = (const int*)d_in[1];
    const int*   src    = ei;
    const int*   dst    = ei + E;
    const int*   batch  = (const int*)d_in[2];
    const float* W1     = (const float*)d_in[3];
    const float* as1    = (const float*)d_in[4];
    const float* ad1    = (const float*)d_in[5];
    const float* b1     = (const float*)d_in[6];
    const float* W2     = (const float*)d_in[7];
    const float* as2    = (const float*)d_in[8];
    const float* ad2    = (const float*)d_in[9];
    const float* b2     = (const float*)d_in[10];
    const float* gate_w = (const float*)d_in[11];
    const float* gate_b = (const float*)d_in[12];
    const float* lin_w  = (const float*)d_in[13];
    const float* lin_b  = (const float*)d_in[14];
    const float* cls_w  = (const float*)d_in[15];
    const float* cls_b  = (const float*)d_in[16];
    float* outp = (float*)d_out;

    char* ws = (char*)d_ws;
    size_t o = 0;
    auto alloc = [&](size_t bytes) -> char* {
        char* p = ws + o;
        o = (o + bytes + 255) & ~(size_t)255;
        return p;
    };

    int*   gs      = (int*)alloc((G + 1) * sizeof(int));
    int*   hist    = (int*)alloc(256 * sizeof(int));
    int*   binbase = (int*)alloc(256 * sizeof(int));
    int*   cursor  = (int*)alloc(256 * sizeof(int));
    int*   off     = (int*)alloc((N + 1) * sizeof(int));
    int*   col     = (int*)alloc((size_t)E * sizeof(int));
    float* als     = (float*)alloc((size_t)N * H * sizeof(float));
    float* ald     = (float*)alloc((size_t)N * H * sizeof(float));
    float* hw      = (float*)alloc((size_t)N * FD * sizeof(float));
    float* h1      = (float*)alloc((size_t)N * FD * sizeof(float));
    float* hsm     = (float*)alloc((size_t)N * FD * sizeof(float));
    float* Mp      = (float*)alloc((size_t)G * NCH * FD * sizeof(float));
    float* Sp      = (float*)alloc((size_t)G * NCH * FD * sizeof(float));
    float* Mm      = (float*)alloc((size_t)G * FD * sizeof(float));
    float* Sinv    = (float*)alloc((size_t)G * FD * sizeof(float));
    float* gl      = (float*)alloc((size_t)N * sizeof(float));
    float* Mg      = (float*)alloc(G * sizeof(float));
    float* iSg     = (float*)alloc(G * sizeof(float));
    float* hg      = (float*)alloc((size_t)G * FD * sizeof(float));

    // part[] aliases hw[]: part is dead after k_fine; hw is first written by
    // k_gemm_al afterwards (stream-ordered), and 6.4MB <= 25.6MB.
    unsigned int* part = (unsigned int*)hw;

    int nbN = (N + 255) / 256;   // 196

    // CSR build (two-level partition, no random-address atomics)
    k_zero<<<32, 256, 0, stream>>>(hist, hg);
    k_graph_starts<<<nbN, 256, 0, stream>>>(batch, gs);
    k_hist<<<NBLK_E, 256, 0, stream>>>(dst, hist);
    k_binscan<<<1, 256, 0, stream>>>(hist, binbase, cursor, off);
    k_partition<<<NBLK_E, 256, 0, stream>>>(src, dst, cursor, part);
    k_fine<<<NBIN, 256, 0, stream>>>(part, binbase, off, col);

    auto run_layer = [&](const float* hin, const float* W, const float* a_s,
                         const float* a_d, const float* bias) {
        k_gemm_al<<<(N + 127) / 128, 256, 0, stream>>>(hin, W, a_s, a_d, hw, als, ald);
        k_agg<<<(N + 3) / 4, 256, 0, stream>>>(hw, als, ald, off, col, bias, h1);
        k_colstats_part<<<dim3(G, NCH), 128, 0, stream>>>(h1, gs, Mp, Sp);
        k_colstats_comb<<<G, 128, 0, stream>>>(Mp, Sp, Mm, Sinv);
        k_softmax_gate<<<(N + 3) / 4, 256, 0, stream>>>(h1, batch, Mm, Sinv, gate_w, gate_b, hsm, gl);
        k_gatestats<<<G, 256, 0, stream>>>(gl, gs, Mg, iSg);
        k_pool<<<dim3(G, NCH), 128, 0, stream>>>(hsm, gl, gs, Mg, iSg, hg);
    };

    run_layer(x, W1, as1, ad1, b1);
    run_layer(hsm, W2, as2, ad2, b2);

    k_head<<<G, 64, 0, stream>>>(hg, lin_w, lin_b, cls_w, cls_b, outp);
}

// Round 5
// 574.917 us; speedup vs baseline: 1.2688x; 1.0059x over previous
//
#include <hip/hip_runtime.h>
#include <math.h>

// Problem constants (fixed by the reference)
constexpr int N    = 50000;
constexpr int E    = 1600000;
constexpr int FD   = 128;   // feature dim (in and out of both GAT layers)
constexpr int H    = 4;     // heads
constexpr int G    = 64;    // graphs
constexpr int NCH  = 16;    // node-chunks per graph for parallel reductions
constexpr int OUT  = 10;

// CSR-build partition parameters
constexpr int NBIN   = (N + 255) / 256;        // 196 bins of 256 nodes (bin = dst>>8)
constexpr int EPB    = 4096;                   // edges per partition block
constexpr int NBLK_E = (E + EPB - 1) / EPB;    // 391

#define DEV __device__ __forceinline__

DEV void fma4(float4& a, float s, const float4& w) {
    a.x = fmaf(s, w.x, a.x); a.y = fmaf(s, w.y, a.y);
    a.z = fmaf(s, w.z, a.z); a.w = fmaf(s, w.w, a.w);
}

DEV float lrelu_exp(float z) {             // exp(leaky_relu(z, 0.2))
    return __expf(z > 0.f ? z : 0.2f * z);
}

// ---------------- setup kernels ----------------

__global__ void k_zero(int* __restrict__ hist, float* __restrict__ hg) {
    int i = blockIdx.x * 256 + threadIdx.x;
    if (i < NBIN) hist[i] = 0;
    if (i < G * FD) hg[i] = 0.f;
}

__global__ void k_graph_starts(const int* __restrict__ batch, int* __restrict__ gs) {
    int i = blockIdx.x * 256 + threadIdx.x;
    if (i >= N) return;
    int b  = batch[i];
    int pb = (i == 0) ? -1 : batch[i - 1];
    for (int g = pb + 1; g <= b; ++g) gs[g] = i;
    if (i == N - 1) for (int g = b + 1; g <= G; ++g) gs[g] = N;
}

// Coarse histogram: 196 bins, LDS-aggregated (196 global atomics per block).
__global__ __launch_bounds__(256)
void k_hist(const int* __restrict__ dst, int* __restrict__ hist) {
    __shared__ int lh[NBIN];
    int t = threadIdx.x;
    for (int i = t; i < NBIN; i += 256) lh[i] = 0;
    __syncthreads();
    int base = blockIdx.x * EPB;
#pragma unroll
    for (int j = 0; j < EPB / 256; ++j) {
        int e = base + j * 256 + t;
        if (e < E) atomicAdd(&lh[dst[e] >> 8], 1);
    }
    __syncthreads();
    for (int i = t; i < NBIN; i += 256) if (lh[i]) atomicAdd(&hist[i], lh[i]);
}

// Scan bin totals -> bin bases + partition cursors; also off[N]=E.
__global__ __launch_bounds__(256)
void k_binscan(const int* __restrict__ hist, int* __restrict__ binbase,
               int* __restrict__ cursor, int* __restrict__ off) {
    __shared__ int sh[256];
    int t = threadIdx.x;
    int v = (t < NBIN) ? hist[t] : 0;
    sh[t] = v;
    __syncthreads();
    for (int d = 1; d < 256; d <<= 1) {
        int add = (t >= d) ? sh[t - d] : 0;
        __syncthreads();
        sh[t] += add;
        __syncthreads();
    }
    if (t < NBIN) {
        binbase[t] = sh[t] - v;       // exclusive
        cursor[t]  = sh[t] - v;
    }
    if (t == NBIN - 1) binbase[NBIN] = sh[t];   // == E
    if (t == 0) off[N] = E;
}

// Partition edges into bin-contiguous storage. Pack: src (16b) | dstLocal (8b) << 16.
__global__ __launch_bounds__(256)
void k_partition(const int* __restrict__ src, const int* __restrict__ dst,
                 int* __restrict__ cursor, unsigned int* __restrict__ part) {
    __shared__ int lh[NBIN];
    __shared__ int gb[NBIN];
    int t = threadIdx.x;
    for (int i = t; i < NBIN; i += 256) lh[i] = 0;
    __syncthreads();
    int base = blockIdx.x * EPB;
    unsigned int pk[EPB / 256];
    int          pr[EPB / 256];        // (bin<<16) | rank, or -1
#pragma unroll
    for (int j = 0; j < EPB / 256; ++j) {
        int e = base + j * 256 + t;
        if (e < E) {
            int d = dst[e];
            int b = d >> 8;
            int r = atomicAdd(&lh[b], 1);            // local rank within (block,bin)
            pk[j] = (unsigned)src[e] | ((unsigned)(d & 255) << 16);
            pr[j] = (b << 16) | r;
        } else pr[j] = -1;
    }
    __syncthreads();
    for (int i = t; i < NBIN; i += 256) gb[i] = atomicAdd(&cursor[i], lh[i]);
    __syncthreads();
#pragma unroll
    for (int j = 0; j < EPB / 256; ++j) {
        if (pr[j] >= 0) {
            int b = pr[j] >> 16, r = pr[j] & 0xFFFF;
            part[gb[b] + r] = pk[j];
        }
    }
}

// Fine pass: one block per bin -> per-node CSR offsets + bin-local scatter.
__global__ __launch_bounds__(256)
void k_fine(const unsigned int* __restrict__ part, const int* __restrict__ binbase,
            int* __restrict__ off, int* __restrict__ col) {
    __shared__ int lh[256], lo[256], lc[256];
    int b = blockIdx.x, t = threadIdx.x;
    int s = binbase[b], e = binbase[b + 1];
    lh[t] = 0; lc[t] = 0;
    __syncthreads();
    for (int i = s + t; i < e; i += 256) atomicAdd(&lh[part[i] >> 16], 1);
    __syncthreads();
    int v = lh[t];
    lo[t] = v;
    __syncthreads();
    for (int d = 1; d < 256; d <<= 1) {
        int add = (t >= d) ? lo[t - d] : 0;
        __syncthreads();
        lo[t] += add;
        __syncthreads();
    }
    int ex = lo[t] - v;                 // exclusive scan
    __syncthreads();
    lo[t] = ex;
    __syncthreads();
    int node = b * 256 + t;
    if (node < N) off[node] = s + ex;
    for (int i = s + t; i < e; i += 256) {
        unsigned p = part[i];
        int dl = p >> 16;
        int r = atomicAdd(&lc[dl], 1);
        col[s + lo[dl] + r] = (int)(p & 0xFFFFu);
    }
}

// ---------------- GEMM + attention-logit epilogue ----------------
__global__ __launch_bounds__(256, 2)
void k_gemm_al(const float* __restrict__ X, const float* __restrict__ W,
               const float* __restrict__ a_s, const float* __restrict__ a_d,
               float* __restrict__ hw, float* __restrict__ als, float* __restrict__ ald)
{
    __shared__ float xs[128][128];
    int r0 = blockIdx.x * 128;
    int t  = threadIdx.x;

    for (int i = 0; i < 16; ++i) {
        int f   = i * 256 + t;
        int row = f >> 5;
        int colf = (f & 31) * 4;
        float4 v = make_float4(0.f, 0.f, 0.f, 0.f);
        if (r0 + row < N) v = *(const float4*)(X + (size_t)(r0 + row) * FD + colf);
        *(float4*)(&xs[row][colf]) = v;
    }
    __syncthreads();

    int ct = t & 31;
    int rt = t >> 5;
    int c4 = ct * 4;
    int rb = rt * 16;

    float4 acc[16];
#pragma unroll
    for (int r = 0; r < 16; ++r) acc[r] = make_float4(0.f, 0.f, 0.f, 0.f);

    for (int k = 0; k < FD; k += 4) {
        float4 wv0 = *(const float4*)(W + (size_t)(k + 0) * FD + c4);
        float4 wv1 = *(const float4*)(W + (size_t)(k + 1) * FD + c4);
        float4 wv2 = *(const float4*)(W + (size_t)(k + 2) * FD + c4);
        float4 wv3 = *(const float4*)(W + (size_t)(k + 3) * FD + c4);
#pragma unroll
        for (int r = 0; r < 16; ++r) {
            float4 xv = *(const float4*)(&xs[rb + r][k]);
            fma4(acc[r], xv.x, wv0);
            fma4(acc[r], xv.y, wv1);
            fma4(acc[r], xv.z, wv2);
            fma4(acc[r], xv.w, wv3);
        }
    }

    int h  = c4 >> 5;
    int j0 = c4 & 31;
    float as0 = a_s[h * 32 + j0 + 0], as1 = a_s[h * 32 + j0 + 1];
    float as2 = a_s[h * 32 + j0 + 2], as3 = a_s[h * 32 + j0 + 3];
    float ad0 = a_d[h * 32 + j0 + 0], ad1 = a_d[h * 32 + j0 + 1];
    float ad2 = a_d[h * 32 + j0 + 2], ad3 = a_d[h * 32 + j0 + 3];

#pragma unroll
    for (int r = 0; r < 16; ++r) {
        int row = r0 + rb + r;
        bool valid = row < N;
        if (valid) *(float4*)(hw + (size_t)row * FD + c4) = acc[r];
        float ps = acc[r].x * as0 + acc[r].y * as1 + acc[r].z * as2 + acc[r].w * as3;
        float pd = acc[r].x * ad0 + acc[r].y * ad1 + acc[r].z * ad2 + acc[r].w * ad3;
#pragma unroll
        for (int m = 1; m < 8; m <<= 1) {
            ps += __shfl_xor(ps, m, 64);
            pd += __shfl_xor(pd, m, 64);
        }
        if ((ct & 7) == 0 && valid) {
            als[row * H + h] = ps;
            ald[row * H + h] = pd;
        }
    }
}

// ---------------- fused edge softmax + aggregation ----------------
// One wave per dst node. float4/lane: 32 lanes cover one 512B row, so the
// wave processes TWO edges per step (lane halves q=0/1), x4 unrolled ->
// 8 gathers in flight, half the serial chain, half the VALU per edge
// (one v_exp per 2 edges instead of per edge).
__global__ __launch_bounds__(256)
void k_agg(const float* __restrict__ hw, const float* __restrict__ als,
           const float* __restrict__ ald, const int* __restrict__ off,
           const int* __restrict__ col, const float* __restrict__ bias,
           float* __restrict__ h1)
{
    int n = blockIdx.x * 4 + (threadIdx.x >> 6);
    if (n >= N) return;
    int l = threadIdx.x & 63;
    int q = l >> 5;                 // half: edge parity
    int p = l & 31;                 // lane within half: owns cols 4p..4p+3
    int h = p >> 3;                 // head of my columns
    float adn = ald[n * H + h];

    // self-loop: half 0 only (half 1 contributes w=0; row n is cached anyway)
    float4 acc;
    float sumw;
    {
        float w = q ? 0.f : lrelu_exp(als[n * H + h] + adn);
        float4 v = *(const float4*)(hw + (size_t)n * FD + 4 * p);
        acc.x = w * v.x; acc.y = w * v.y; acc.z = w * v.z; acc.w = w * v.w;
        sumw = w;
    }

    int ib = off[n];
    int deg = off[n + 1] - ib;
    int j = 0;
    for (; j + 8 <= deg; j += 8) {          // 4 steps x 2 halves
        int s0 = col[ib + j + 0 + q];
        int s1 = col[ib + j + 2 + q];
        int s2 = col[ib + j + 4 + q];
        int s3 = col[ib + j + 6 + q];
        float z0 = als[s0 * H + h];
        float z1 = als[s1 * H + h];
        float z2 = als[s2 * H + h];
        float z3 = als[s3 * H + h];
        float4 v0 = *(const float4*)(hw + (size_t)s0 * FD + 4 * p);
        float4 v1 = *(const float4*)(hw + (size_t)s1 * FD + 4 * p);
        float4 v2 = *(const float4*)(hw + (size_t)s2 * FD + 4 * p);
        float4 v3 = *(const float4*)(hw + (size_t)s3 * FD + 4 * p);
        float w0 = lrelu_exp(z0 + adn);
        float w1 = lrelu_exp(z1 + adn);
        float w2 = lrelu_exp(z2 + adn);
        float w3 = lrelu_exp(z3 + adn);
        fma4(acc, w0, v0);
        fma4(acc, w1, v1);
        fma4(acc, w2, v2);
        fma4(acc, w3, v3);
        sumw += w0 + w1 + w2 + w3;
    }
    for (; j + 2 <= deg; j += 2) {          // 1 step x 2 halves
        int s = col[ib + j + q];
        float w = lrelu_exp(als[s * H + h] + adn);
        float4 v = *(const float4*)(hw + (size_t)s * FD + 4 * p);
        fma4(acc, w, v);
        sumw += w;
    }
    if (j < deg) {                          // odd leftover: half 0 only
        int s = q ? n : col[ib + j];
        float w = q ? 0.f : lrelu_exp(als[s * H + h] + adn);
        float4 v = *(const float4*)(hw + (size_t)s * FD + 4 * p);
        fma4(acc, w, v);
        sumw += w;
    }

    // merge halves (lane l <-> l+32 hold the same columns)
    acc.x += __shfl_xor(acc.x, 32, 64);
    acc.y += __shfl_xor(acc.y, 32, 64);
    acc.z += __shfl_xor(acc.z, 32, 64);
    acc.w += __shfl_xor(acc.w, 32, 64);
    sumw  += __shfl_xor(sumw,  32, 64);

    if (q == 0) {
        float inv = 1.f / sumw;
        float4 b4 = *(const float4*)(bias + 4 * p);
        float4 o;
        o.x = fmaf(acc.x, inv, b4.x);
        o.y = fmaf(acc.y, inv, b4.y);
        o.z = fmaf(acc.z, inv, b4.z);
        o.w = fmaf(acc.w, inv, b4.w);
        o.x = o.x > 0.f ? o.x : 0.f;
        o.y = o.y > 0.f ? o.y : 0.f;
        o.z = o.z > 0.f ? o.z : 0.f;
        o.w = o.w > 0.f ? o.w : 0.f;
        *(float4*)(h1 + (size_t)n * FD + 4 * p) = o;
    }
}

// ---------------- per-graph column softmax stats (chunked) ----------------
__global__ void k_colstats_part(const float* __restrict__ h1, const int* __restrict__ gs,
                                float* __restrict__ Mp, float* __restrict__ Sp)
{
    int g = blockIdx.x, ch = blockIdx.y, c = threadIdx.x;
    int s = gs[g], e = gs[g + 1];
    int per = (e - s + NCH - 1) / NCH;
    int ns = s + ch * per;
    int ne = min(ns + per, e);
    float m = -3e38f;
    for (int n = ns; n < ne; ++n) m = fmaxf(m, h1[(size_t)n * FD + c]);
    float sum = 0.f;
    for (int n = ns; n < ne; ++n) sum += __expf(h1[(size_t)n * FD + c] - m);
    int o = (g * NCH + ch) * FD + c;
    Mp[o] = m; Sp[o] = sum;
}

__global__ void k_colstats_comb(const float* __restrict__ Mp, const float* __restrict__ Sp,
                                float* __restrict__ Mm, float* __restrict__ Sinv)
{
    int g = blockIdx.x, c = threadIdx.x;
    float m = -3e38f;
#pragma unroll
    for (int ch = 0; ch < NCH; ++ch) m = fmaxf(m, Mp[(g * NCH + ch) * FD + c]);
    float s = 0.f;
#pragma unroll
    for (int ch = 0; ch < NCH; ++ch) {
        float sp = Sp[(g * NCH + ch) * FD + c];
        if (sp > 0.f) s += sp * __expf(Mp[(g * NCH + ch) * FD + c] - m);
    }
    Mm[g * FD + c] = m;
    Sinv[g * FD + c] = 1.f / s;
}

// ---------------- node softmax-normalize + gate logits ----------------
__global__ __launch_bounds__(256)
void k_softmax_gate(const float* __restrict__ h1, const int* __restrict__ batch,
                    const float* __restrict__ Mm, const float* __restrict__ Sinv,
                    const float* __restrict__ gw, const float* __restrict__ gb,
                    float* __restrict__ hsm, float* __restrict__ gl)
{
    int n = blockIdx.x * 4 + (threadIdx.x >> 6);
    if (n >= N) return;
    int l = threadIdx.x & 63;
    int g = batch[n];
    float2 hv = *(const float2*)(h1 + (size_t)n * FD + 2 * l);
    float2 mv = *(const float2*)(Mm + g * FD + 2 * l);
    float2 sv = *(const float2*)(Sinv + g * FD + 2 * l);
    float vx = __expf(hv.x - mv.x) * sv.x;
    float vy = __expf(hv.y - mv.y) * sv.y;
    float2 o = make_float2(vx, vy);
    *(float2*)(hsm + (size_t)n * FD + 2 * l) = o;
    float p = vx * gw[2 * l] + vy * gw[2 * l + 1];
#pragma unroll
    for (int m = 1; m < 64; m <<= 1) p += __shfl_xor(p, m, 64);
    if (l == 0) gl[n] = p + gb[0];
}

// ---------------- per-graph gate softmax stats ----------------
__global__ __launch_bounds__(256)
void k_gatestats(const float* __restrict__ gl, const int* __restrict__ gs,
                 float* __restrict__ Mg, float* __restrict__ iSg)
{
    __shared__ float red[8];
    int g = blockIdx.x;
    int s = gs[g], e = gs[g + 1];
    int t = threadIdx.x;
    float m = -3e38f;
    for (int i = s + t; i < e; i += 256) m = fmaxf(m, gl[i]);
#pragma unroll
    for (int mk = 1; mk < 64; mk <<= 1) m = fmaxf(m, __shfl_xor(m, mk, 64));
    if ((t & 63) == 0) red[t >> 6] = m;
    __syncthreads();
    if (t == 0) {
        float mm = red[0];
        for (int w2 = 1; w2 < 4; ++w2) mm = fmaxf(mm, red[w2]);
        red[0] = mm;
    }
    __syncthreads();
    m = red[0];
    float sum = 0.f;
    for (int i = s + t; i < e; i += 256) sum += __expf(gl[i] - m);
#pragma unroll
    for (int mk = 1; mk < 64; mk <<= 1) sum += __shfl_xor(sum, mk, 64);
    if ((t & 63) == 0) red[4 + (t >> 6)] = sum;
    __syncthreads();
    if (t == 0) {
        float ss = red[4] + red[5] + red[6] + red[7];
        Mg[g] = m;
        iSg[g] = 1.f / ss;
    }
}

// ---------------- gated pooling (chunked, atomic accumulate into hg) ----------------
__global__ void k_pool(const float* __restrict__ hsm, const float* __restrict__ gl,
                       const int* __restrict__ gs, const float* __restrict__ Mg,
                       const float* __restrict__ iSg, float* __restrict__ hg)
{
    int g = blockIdx.x, ch = blockIdx.y, c = threadIdx.x;
    int s = gs[g], e = gs[g + 1];
    int per = (e - s + NCH - 1) / NCH;
    int ns = s + ch * per;
    int ne = min(ns + per, e);
    float mg = Mg[g], is = iSg[g];
    float acc = 0.f;
    for (int n = ns; n < ne; ++n)
        acc = fmaf(__expf(gl[n] - mg) * is, hsm[(size_t)n * FD + c], acc);
    atomicAdd(&hg[g * FD + c], acc);
}

// ---------------- final MLP head ----------------
__global__ __launch_bounds__(64)
void k_head(const float* __restrict__ hg, const float* __restrict__ lin_w,
            const float* __restrict__ lin_b, const float* __restrict__ cls_w,
            const float* __restrict__ cls_b, float* __restrict__ out)
{
    __shared__ float hrow[128];
    __shared__ float tbuf[64];
    int g = blockIdx.x, j = threadIdx.x;
    hrow[j]      = hg[g * FD + j];
    hrow[j + 64] = hg[g * FD + j + 64];
    __syncthreads();
    float a = lin_b[j];
    for (int c = 0; c < 128; ++c) a = fmaf(hrow[c], lin_w[c * 64 + j], a);
    tbuf[j] = a > 0.f ? a : 0.f;
    __syncthreads();
    if (j < OUT) {
        float o = cls_b[j];
        for (int k = 0; k < 64; ++k) o = fmaf(tbuf[k], cls_w[k * OUT + j], o);
        out[g * OUT + j] = o;
    }
}

// ---------------- host launcher ----------------
extern "C" void kernel_launch(void* const* d_in, const int* in_sizes, int n_in,
                              void* d_out, int out_size, void* d_ws, size_t ws_size,
                              hipStream_t stream)
{
    const float* x      = (const float*)d_in[0];
    const int*   ei     = (const int*)d_in[1];
    const int*   src    = ei;
    const int*   dst    = ei + E;
    const int*   batch  = (const int*)d_in[2];
    const float* W1     = (const float*)d_in[3];
    const float* as1    = (const float*)d_in[4];
    const float* ad1    = (const float*)d_in[5];
    const float* b1     = (const float*)d_in[6];
    const float* W2     = (const float*)d_in[7];
    const float* as2    = (const float*)d_in[8];
    const float* ad2    = (const float*)d_in[9];
    const float* b2     = (const float*)d_in[10];
    const float* gate_w = (const float*)d_in[11];
    const float* gate_b = (const float*)d_in[12];
    const float* lin_w  = (const float*)d_in[13];
    const float* lin_b  = (const float*)d_in[14];
    const float* cls_w  = (const float*)d_in[15];
    const float* cls_b  = (const float*)d_in[16];
    float* outp = (float*)d_out;

    char* ws = (char*)d_ws;
    size_t o = 0;
    auto alloc = [&](size_t bytes) -> char* {
        char* p = ws + o;
        o = (o + bytes + 255) & ~(size_t)255;
        return p;
    };

    int*   gs      = (int*)alloc((G + 1) * sizeof(int));
    int*   hist    = (int*)alloc(256 * sizeof(int));
    int*   binbase = (int*)alloc(256 * sizeof(int));
    int*   cursor  = (int*)alloc(256 * sizeof(int));
    int*   off     = (int*)alloc((N + 1) * sizeof(int));
    int*   col     = (int*)alloc((size_t)E * sizeof(int));
    float* als     = (float*)alloc((size_t)N * H * sizeof(float));
    float* ald     = (float*)alloc((size_t)N * H * sizeof(float));
    float* hw      = (float*)alloc((size_t)N * FD * sizeof(float));
    float* h1      = (float*)alloc((size_t)N * FD * sizeof(float));
    float* hsm     = (float*)alloc((size_t)N * FD * sizeof(float));
    float* Mp      = (float*)alloc((size_t)G * NCH * FD * sizeof(float));
    float* Sp      = (float*)alloc((size_t)G * NCH * FD * sizeof(float));
    float* Mm      = (float*)alloc((size_t)G * FD * sizeof(float));
    float* Sinv    = (float*)alloc((size_t)G * FD * sizeof(float));
    float* gl      = (float*)alloc((size_t)N * sizeof(float));
    float* Mg      = (float*)alloc(G * sizeof(float));
    float* iSg     = (float*)alloc(G * sizeof(float));
    float* hg      = (float*)alloc((size_t)G * FD * sizeof(float));

    // part[] aliases hw[]: part is dead after k_fine; hw is first written by
    // k_gemm_al afterwards (stream-ordered), and 6.4MB <= 25.6MB.
    unsigned int* part = (unsigned int*)hw;

    int nbN = (N + 255) / 256;   // 196

    // CSR build (two-level partition, no random-address atomics)
    k_zero<<<32, 256, 0, stream>>>(hist, hg);
    k_graph_starts<<<nbN, 256, 0, stream>>>(batch, gs);
    k_hist<<<NBLK_E, 256, 0, stream>>>(dst, hist);
    k_binscan<<<1, 256, 0, stream>>>(hist, binbase, cursor, off);
    k_partition<<<NBLK_E, 256, 0, stream>>>(src, dst, cursor, part);
    k_fine<<<NBIN, 256, 0, stream>>>(part, binbase, off, col);

    auto run_layer = [&](const float* hin, const float* W, const float* a_s,
                         const float* a_d, const float* bias) {
        k_gemm_al<<<(N + 127) / 128, 256, 0, stream>>>(hin, W, a_s, a_d, hw, als, ald);
        k_agg<<<(N + 3) / 4, 256, 0, stream>>>(hw, als, ald, off, col, bias, h1);
        k_colstats_part<<<dim3(G, NCH), 128, 0, stream>>>(h1, gs, Mp, Sp);
        k_colstats_comb<<<G, 128, 0, stream>>>(Mp, Sp, Mm, Sinv);
        k_softmax_gate<<<(N + 3) / 4, 256, 0, stream>>>(h1, batch, Mm, Sinv, gate_w, gate_b, hsm, gl);
        k_gatestats<<<G, 256, 0, stream>>>(gl, gs, Mg, iSg);
        k_pool<<<dim3(G, NCH), 128, 0, stream>>>(hsm, gl, gs, Mg, iSg, hg);
    };

    run_layer(x, W1, as1, ad1, b1);
    run_layer(hsm, W2, as2, ad2, b2);

    k_head<<<G, 64, 0, stream>>>(hg, lin_w, lin_b, cls_w, cls_b, outp);
}

// Round 6
// 459.764 us; speedup vs baseline: 1.5866x; 1.2505x over previous
//
#include <hip/hip_runtime.h>
#include <hip/hip_fp16.h>
#include <math.h>

// Problem constants (fixed by the reference)
constexpr int N    = 50000;
constexpr int E    = 1600000;
constexpr int FD   = 128;   // feature dim (in and out of both GAT layers)
constexpr int H    = 4;     // heads
constexpr int G    = 64;    // graphs
constexpr int NCH  = 16;    // node-chunks per graph for parallel reductions
constexpr int OUT  = 10;

// CSR-build partition parameters
constexpr int NBIN   = (N + 255) / 256;        // 196 bins of 256 nodes (bin = dst>>8)
constexpr int EPB    = 4096;                   // edges per partition block
constexpr int NBLK_E = (E + EPB - 1) / EPB;    // 391

#define DEV __device__ __forceinline__

DEV void fma4(float4& a, float s, const float4& w) {
    a.x = fmaf(s, w.x, a.x); a.y = fmaf(s, w.y, a.y);
    a.z = fmaf(s, w.z, a.z); a.w = fmaf(s, w.w, a.w);
}

DEV float lrelu_exp(float z) {             // exp(leaky_relu(z, 0.2))
    return __expf(z > 0.f ? z : 0.2f * z);
}

union HF4 {                                // 4 halfs <-> one 8B word
    float2  f;
    __half2 h[2];
};

DEV void fmah(float4& a, float w, const HF4& u) {
    float2 lo = __half22float2(u.h[0]);
    float2 hi = __half22float2(u.h[1]);
    a.x = fmaf(w, lo.x, a.x); a.y = fmaf(w, lo.y, a.y);
    a.z = fmaf(w, hi.x, a.z); a.w = fmaf(w, hi.y, a.w);
}

// ---------------- setup kernels ----------------

__global__ void k_zero(int* __restrict__ hist, float* __restrict__ hg) {
    int i = blockIdx.x * 256 + threadIdx.x;
    if (i < NBIN) hist[i] = 0;
    if (i < G * FD) hg[i] = 0.f;
}

__global__ void k_graph_starts(const int* __restrict__ batch, int* __restrict__ gs) {
    int i = blockIdx.x * 256 + threadIdx.x;
    if (i >= N) return;
    int b  = batch[i];
    int pb = (i == 0) ? -1 : batch[i - 1];
    for (int g = pb + 1; g <= b; ++g) gs[g] = i;
    if (i == N - 1) for (int g = b + 1; g <= G; ++g) gs[g] = N;
}

// Coarse histogram: 196 bins, LDS-aggregated.
__global__ __launch_bounds__(256)
void k_hist(const int* __restrict__ dst, int* __restrict__ hist) {
    __shared__ int lh[NBIN];
    int t = threadIdx.x;
    for (int i = t; i < NBIN; i += 256) lh[i] = 0;
    __syncthreads();
    int base = blockIdx.x * EPB;
#pragma unroll
    for (int j = 0; j < EPB / 256; ++j) {
        int e = base + j * 256 + t;
        if (e < E) atomicAdd(&lh[dst[e] >> 8], 1);
    }
    __syncthreads();
    for (int i = t; i < NBIN; i += 256) if (lh[i]) atomicAdd(&hist[i], lh[i]);
}

// Scan bin totals -> bin bases + partition cursors; also off[N]=E.
__global__ __launch_bounds__(256)
void k_binscan(const int* __restrict__ hist, int* __restrict__ binbase,
               int* __restrict__ cursor, int* __restrict__ off) {
    __shared__ int sh[256];
    int t = threadIdx.x;
    int v = (t < NBIN) ? hist[t] : 0;
    sh[t] = v;
    __syncthreads();
    for (int d = 1; d < 256; d <<= 1) {
        int add = (t >= d) ? sh[t - d] : 0;
        __syncthreads();
        sh[t] += add;
        __syncthreads();
    }
    if (t < NBIN) {
        binbase[t] = sh[t] - v;       // exclusive
        cursor[t]  = sh[t] - v;
    }
    if (t == NBIN - 1) binbase[NBIN] = sh[t];   // == E
    if (t == 0) off[N] = E;
}

// Partition edges into bin-contiguous storage. Pack: src (16b) | dstLocal (8b) << 16.
__global__ __launch_bounds__(256)
void k_partition(const int* __restrict__ src, const int* __restrict__ dst,
                 int* __restrict__ cursor, unsigned int* __restrict__ part) {
    __shared__ int lh[NBIN];
    __shared__ int gb[NBIN];
    int t = threadIdx.x;
    for (int i = t; i < NBIN; i += 256) lh[i] = 0;
    __syncthreads();
    int base = blockIdx.x * EPB;
    unsigned int pk[EPB / 256];
    int          pr[EPB / 256];        // (bin<<16) | rank, or -1
#pragma unroll
    for (int j = 0; j < EPB / 256; ++j) {
        int e = base + j * 256 + t;
        if (e < E) {
            int d = dst[e];
            int b = d >> 8;
            int r = atomicAdd(&lh[b], 1);            // local rank within (block,bin)
            pk[j] = (unsigned)src[e] | ((unsigned)(d & 255) << 16);
            pr[j] = (b << 16) | r;
        } else pr[j] = -1;
    }
    __syncthreads();
    for (int i = t; i < NBIN; i += 256) gb[i] = atomicAdd(&cursor[i], lh[i]);
    __syncthreads();
#pragma unroll
    for (int j = 0; j < EPB / 256; ++j) {
        if (pr[j] >= 0) {
            int b = pr[j] >> 16, r = pr[j] & 0xFFFF;
            part[gb[b] + r] = pk[j];
        }
    }
}

// Fine pass: one block per bin -> per-node CSR offsets + bin-local scatter.
__global__ __launch_bounds__(256)
void k_fine(const unsigned int* __restrict__ part, const int* __restrict__ binbase,
            int* __restrict__ off, int* __restrict__ col) {
    __shared__ int lh[256], lo[256], lc[256];
    int b = blockIdx.x, t = threadIdx.x;
    int s = binbase[b], e = binbase[b + 1];
    lh[t] = 0; lc[t] = 0;
    __syncthreads();
    for (int i = s + t; i < e; i += 256) atomicAdd(&lh[part[i] >> 16], 1);
    __syncthreads();
    int v = lh[t];
    lo[t] = v;
    __syncthreads();
    for (int d = 1; d < 256; d <<= 1) {
        int add = (t >= d) ? lo[t - d] : 0;
        __syncthreads();
        lo[t] += add;
        __syncthreads();
    }
    int ex = lo[t] - v;                 // exclusive scan
    __syncthreads();
    lo[t] = ex;
    __syncthreads();
    int node = b * 256 + t;
    if (node < N) off[node] = s + ex;
    for (int i = s + t; i < e; i += 256) {
        unsigned p = part[i];
        int dl = p >> 16;
        int r = atomicAdd(&lc[dl], 1);
        col[s + lo[dl] + r] = (int)(p & 0xFFFFu);
    }
}

// ---------------- GEMM + attention-logit epilogue ----------------
// hw is written in FP16 (k_agg is its only consumer; halves gather bytes).
__global__ __launch_bounds__(256, 2)
void k_gemm_al(const float* __restrict__ X, const float* __restrict__ W,
               const float* __restrict__ a_s, const float* __restrict__ a_d,
               __half* __restrict__ hw, float* __restrict__ als, float* __restrict__ ald)
{
    __shared__ float xs[128][128];
    int r0 = blockIdx.x * 128;
    int t  = threadIdx.x;

    for (int i = 0; i < 16; ++i) {
        int f   = i * 256 + t;
        int row = f >> 5;
        int colf = (f & 31) * 4;
        float4 v = make_float4(0.f, 0.f, 0.f, 0.f);
        if (r0 + row < N) v = *(const float4*)(X + (size_t)(r0 + row) * FD + colf);
        *(float4*)(&xs[row][colf]) = v;
    }
    __syncthreads();

    int ct = t & 31;
    int rt = t >> 5;
    int c4 = ct * 4;
    int rb = rt * 16;

    float4 acc[16];
#pragma unroll
    for (int r = 0; r < 16; ++r) acc[r] = make_float4(0.f, 0.f, 0.f, 0.f);

    for (int k = 0; k < FD; k += 4) {
        float4 wv0 = *(const float4*)(W + (size_t)(k + 0) * FD + c4);
        float4 wv1 = *(const float4*)(W + (size_t)(k + 1) * FD + c4);
        float4 wv2 = *(const float4*)(W + (size_t)(k + 2) * FD + c4);
        float4 wv3 = *(const float4*)(W + (size_t)(k + 3) * FD + c4);
#pragma unroll
        for (int r = 0; r < 16; ++r) {
            float4 xv = *(const float4*)(&xs[rb + r][k]);
            fma4(acc[r], xv.x, wv0);
            fma4(acc[r], xv.y, wv1);
            fma4(acc[r], xv.z, wv2);
            fma4(acc[r], xv.w, wv3);
        }
    }

    int h  = c4 >> 5;
    int j0 = c4 & 31;
    float as0 = a_s[h * 32 + j0 + 0], as1 = a_s[h * 32 + j0 + 1];
    float as2 = a_s[h * 32 + j0 + 2], as3 = a_s[h * 32 + j0 + 3];
    float ad0 = a_d[h * 32 + j0 + 0], ad1 = a_d[h * 32 + j0 + 1];
    float ad2 = a_d[h * 32 + j0 + 2], ad3 = a_d[h * 32 + j0 + 3];

#pragma unroll
    for (int r = 0; r < 16; ++r) {
        int row = r0 + rb + r;
        bool valid = row < N;
        if (valid) {
            HF4 u;
            u.h[0] = __floats2half2_rn(acc[r].x, acc[r].y);
            u.h[1] = __floats2half2_rn(acc[r].z, acc[r].w);
            *(float2*)(hw + (size_t)row * FD + c4) = u.f;
        }
        float ps = acc[r].x * as0 + acc[r].y * as1 + acc[r].z * as2 + acc[r].w * as3;
        float pd = acc[r].x * ad0 + acc[r].y * ad1 + acc[r].z * ad2 + acc[r].w * ad3;
#pragma unroll
        for (int m = 1; m < 8; m <<= 1) {
            ps += __shfl_xor(ps, m, 64);
            pd += __shfl_xor(pd, m, 64);
        }
        if ((ct & 7) == 0 && valid) {
            als[row * H + h] = ps;
            ald[row * H + h] = pd;
        }
    }
}

// ---------------- fused edge softmax + aggregation ----------------
// One wave per dst node; fp16 rows (256B): 32 lanes x 8B cover one row, so
// the wave processes TWO edges per step (lane halves q=0/1) x4 unrolled ->
// 8 gathers in flight. f32 accumulate in registers.
__global__ __launch_bounds__(256)
void k_agg(const __half* __restrict__ hw, const float* __restrict__ als,
           const float* __restrict__ ald, const int* __restrict__ off,
           const int* __restrict__ col, const float* __restrict__ bias,
           float* __restrict__ h1)
{
    int n = blockIdx.x * 4 + (threadIdx.x >> 6);
    if (n >= N) return;
    int l = threadIdx.x & 63;
    int q = l >> 5;                 // half: edge parity
    int p = l & 31;                 // lane within half: owns cols 4p..4p+3
    int h = p >> 3;                 // head of my columns
    float adn = ald[n * H + h];

    // self-loop: half 0 only
    float4 acc = make_float4(0.f, 0.f, 0.f, 0.f);
    float sumw;
    {
        float w = q ? 0.f : lrelu_exp(als[n * H + h] + adn);
        HF4 u; u.f = *(const float2*)(hw + (size_t)n * FD + 4 * p);
        fmah(acc, w, u);
        sumw = w;
    }

    int ib = off[n];
    int deg = off[n + 1] - ib;
    int j = 0;
    for (; j + 8 <= deg; j += 8) {          // 4 steps x 2 halves
        int s0 = col[ib + j + 0 + q];
        int s1 = col[ib + j + 2 + q];
        int s2 = col[ib + j + 4 + q];
        int s3 = col[ib + j + 6 + q];
        float z0 = als[s0 * H + h];
        float z1 = als[s1 * H + h];
        float z2 = als[s2 * H + h];
        float z3 = als[s3 * H + h];
        HF4 u0; u0.f = *(const float2*)(hw + (size_t)s0 * FD + 4 * p);
        HF4 u1; u1.f = *(const float2*)(hw + (size_t)s1 * FD + 4 * p);
        HF4 u2; u2.f = *(const float2*)(hw + (size_t)s2 * FD + 4 * p);
        HF4 u3; u3.f = *(const float2*)(hw + (size_t)s3 * FD + 4 * p);
        float w0 = lrelu_exp(z0 + adn);
        float w1 = lrelu_exp(z1 + adn);
        float w2 = lrelu_exp(z2 + adn);
        float w3 = lrelu_exp(z3 + adn);
        fmah(acc, w0, u0);
        fmah(acc, w1, u1);
        fmah(acc, w2, u2);
        fmah(acc, w3, u3);
        sumw += w0 + w1 + w2 + w3;
    }
    for (; j + 2 <= deg; j += 2) {          // 1 step x 2 halves
        int s = col[ib + j + q];
        float w = lrelu_exp(als[s * H + h] + adn);
        HF4 u; u.f = *(const float2*)(hw + (size_t)s * FD + 4 * p);
        fmah(acc, w, u);
        sumw += w;
    }
    if (j < deg) {                          // odd leftover: half 0 only
        int s = q ? n : col[ib + j];
        float w = q ? 0.f : lrelu_exp(als[s * H + h] + adn);
        HF4 u; u.f = *(const float2*)(hw + (size_t)s * FD + 4 * p);
        fmah(acc, w, u);
        sumw += w;
    }

    // merge halves (lane l <-> l+32 hold the same columns)
    acc.x += __shfl_xor(acc.x, 32, 64);
    acc.y += __shfl_xor(acc.y, 32, 64);
    acc.z += __shfl_xor(acc.z, 32, 64);
    acc.w += __shfl_xor(acc.w, 32, 64);
    sumw  += __shfl_xor(sumw,  32, 64);

    if (q == 0) {
        float inv = 1.f / sumw;
        float4 b4 = *(const float4*)(bias + 4 * p);
        float4 o;
        o.x = fmaf(acc.x, inv, b4.x);
        o.y = fmaf(acc.y, inv, b4.y);
        o.z = fmaf(acc.z, inv, b4.z);
        o.w = fmaf(acc.w, inv, b4.w);
        o.x = o.x > 0.f ? o.x : 0.f;
        o.y = o.y > 0.f ? o.y : 0.f;
        o.z = o.z > 0.f ? o.z : 0.f;
        o.w = o.w > 0.f ? o.w : 0.f;
        *(float4*)(h1 + (size_t)n * FD + 4 * p) = o;
    }
}

// ---------------- per-graph column softmax stats (chunked) ----------------
__global__ void k_colstats_part(const float* __restrict__ h1, const int* __restrict__ gs,
                                float* __restrict__ Mp, float* __restrict__ Sp)
{
    int g = blockIdx.x, ch = blockIdx.y, c = threadIdx.x;
    int s = gs[g], e = gs[g + 1];
    int per = (e - s + NCH - 1) / NCH;
    int ns = s + ch * per;
    int ne = min(ns + per, e);
    float m = -3e38f;
    for (int n = ns; n < ne; ++n) m = fmaxf(m, h1[(size_t)n * FD + c]);
    float sum = 0.f;
    for (int n = ns; n < ne; ++n) sum += __expf(h1[(size_t)n * FD + c] - m);
    int o = (g * NCH + ch) * FD + c;
    Mp[o] = m; Sp[o] = sum;
}

__global__ void k_colstats_comb(const float* __restrict__ Mp, const float* __restrict__ Sp,
                                float* __restrict__ Mm, float* __restrict__ Sinv)
{
    int g = blockIdx.x, c = threadIdx.x;
    float m = -3e38f;
#pragma unroll
    for (int ch = 0; ch < NCH; ++ch) m = fmaxf(m, Mp[(g * NCH + ch) * FD + c]);
    float s = 0.f;
#pragma unroll
    for (int ch = 0; ch < NCH; ++ch) {
        float sp = Sp[(g * NCH + ch) * FD + c];
        if (sp > 0.f) s += sp * __expf(Mp[(g * NCH + ch) * FD + c] - m);
    }
    Mm[g * FD + c] = m;
    Sinv[g * FD + c] = 1.f / s;
}

// ---------------- node softmax-normalize + gate logits ----------------
__global__ __launch_bounds__(256)
void k_softmax_gate(const float* __restrict__ h1, const int* __restrict__ batch,
                    const float* __restrict__ Mm, const float* __restrict__ Sinv,
                    const float* __restrict__ gw, const float* __restrict__ gb,
                    float* __restrict__ hsm, float* __restrict__ gl)
{
    int n = blockIdx.x * 4 + (threadIdx.x >> 6);
    if (n >= N) return;
    int l = threadIdx.x & 63;
    int g = batch[n];
    float2 hv = *(const float2*)(h1 + (size_t)n * FD + 2 * l);
    float2 mv = *(const float2*)(Mm + g * FD + 2 * l);
    float2 sv = *(const float2*)(Sinv + g * FD + 2 * l);
    float vx = __expf(hv.x - mv.x) * sv.x;
    float vy = __expf(hv.y - mv.y) * sv.y;
    float2 o = make_float2(vx, vy);
    *(float2*)(hsm + (size_t)n * FD + 2 * l) = o;
    float p = vx * gw[2 * l] + vy * gw[2 * l + 1];
#pragma unroll
    for (int m = 1; m < 64; m <<= 1) p += __shfl_xor(p, m, 64);
    if (l == 0) gl[n] = p + gb[0];
}

// ---------------- per-graph gate softmax stats ----------------
__global__ __launch_bounds__(256)
void k_gatestats(const float* __restrict__ gl, const int* __restrict__ gs,
                 float* __restrict__ Mg, float* __restrict__ iSg)
{
    __shared__ float red[8];
    int g = blockIdx.x;
    int s = gs[g], e = gs[g + 1];
    int t = threadIdx.x;
    float m = -3e38f;
    for (int i = s + t; i < e; i += 256) m = fmaxf(m, gl[i]);
#pragma unroll
    for (int mk = 1; mk < 64; mk <<= 1) m = fmaxf(m, __shfl_xor(m, mk, 64));
    if ((t & 63) == 0) red[t >> 6] = m;
    __syncthreads();
    if (t == 0) {
        float mm = red[0];
        for (int w2 = 1; w2 < 4; ++w2) mm = fmaxf(mm, red[w2]);
        red[0] = mm;
    }
    __syncthreads();
    m = red[0];
    float sum = 0.f;
    for (int i = s + t; i < e; i += 256) sum += __expf(gl[i] - m);
#pragma unroll
    for (int mk = 1; mk < 64; mk <<= 1) sum += __shfl_xor(sum, mk, 64);
    if ((t & 63) == 0) red[4 + (t >> 6)] = sum;
    __syncthreads();
    if (t == 0) {
        float ss = red[4] + red[5] + red[6] + red[7];
        Mg[g] = m;
        iSg[g] = 1.f / ss;
    }
}

// ---------------- gated pooling (chunked, atomic accumulate into hg) ----------------
__global__ void k_pool(const float* __restrict__ hsm, const float* __restrict__ gl,
                       const int* __restrict__ gs, const float* __restrict__ Mg,
                       const float* __restrict__ iSg, float* __restrict__ hg)
{
    int g = blockIdx.x, ch = blockIdx.y, c = threadIdx.x;
    int s = gs[g], e = gs[g + 1];
    int per = (e - s + NCH - 1) / NCH;
    int ns = s + ch * per;
    int ne = min(ns + per, e);
    float mg = Mg[g], is = iSg[g];
    float acc = 0.f;
    for (int n = ns; n < ne; ++n)
        acc = fmaf(__expf(gl[n] - mg) * is, hsm[(size_t)n * FD + c], acc);
    atomicAdd(&hg[g * FD + c], acc);
}

// ---------------- final MLP head ----------------
__global__ __launch_bounds__(64)
void k_head(const float* __restrict__ hg, const float* __restrict__ lin_w,
            const float* __restrict__ lin_b, const float* __restrict__ cls_w,
            const float* __restrict__ cls_b, float* __restrict__ out)
{
    __shared__ float hrow[128];
    __shared__ float tbuf[64];
    int g = blockIdx.x, j = threadIdx.x;
    hrow[j]      = hg[g * FD + j];
    hrow[j + 64] = hg[g * FD + j + 64];
    __syncthreads();
    float a = lin_b[j];
    for (int c = 0; c < 128; ++c) a = fmaf(hrow[c], lin_w[c * 64 + j], a);
    tbuf[j] = a > 0.f ? a : 0.f;
    __syncthreads();
    if (j < OUT) {
        float o = cls_b[j];
        for (int k = 0; k < 64; ++k) o = fmaf(tbuf[k], cls_w[k * OUT + j], o);
        out[g * OUT + j] = o;
    }
}

// ---------------- host launcher ----------------
extern "C" void kernel_launch(void* const* d_in, const int* in_sizes, int n_in,
                              void* d_out, int out_size, void* d_ws, size_t ws_size,
                              hipStream_t stream)
{
    const float* x      = (const float*)d_in[0];
    const int*   ei     = (const int*)d_in[1];
    const int*   src    = ei;
    const int*   dst    = ei + E;
    const int*   batch  = (const int*)d_in[2];
    const float* W1     = (const float*)d_in[3];
    const float* as1    = (const float*)d_in[4];
    const float* ad1    = (const float*)d_in[5];
    const float* b1     = (const float*)d_in[6];
    const float* W2     = (const float*)d_in[7];
    const float* as2    = (const float*)d_in[8];
    const float* ad2    = (const float*)d_in[9];
    const float* b2     = (const float*)d_in[10];
    const float* gate_w = (const float*)d_in[11];
    const float* gate_b = (const float*)d_in[12];
    const float* lin_w  = (const float*)d_in[13];
    const float* lin_b  = (const float*)d_in[14];
    const float* cls_w  = (const float*)d_in[15];
    const float* cls_b  = (const float*)d_in[16];
    float* outp = (float*)d_out;

    char* ws = (char*)d_ws;
    size_t o = 0;
    auto alloc = [&](size_t bytes) -> char* {
        char* p = ws + o;
        o = (o + bytes + 255) & ~(size_t)255;
        return p;
    };

    int*    gs      = (int*)alloc((G + 1) * sizeof(int));
    int*    hist    = (int*)alloc(256 * sizeof(int));
    int*    binbase = (int*)alloc(256 * sizeof(int));
    int*    cursor  = (int*)alloc(256 * sizeof(int));
    int*    off     = (int*)alloc((N + 1) * sizeof(int));
    int*    col     = (int*)alloc((size_t)E * sizeof(int));
    float*  als     = (float*)alloc((size_t)N * H * sizeof(float));
    float*  ald     = (float*)alloc((size_t)N * H * sizeof(float));
    __half* hw      = (__half*)alloc((size_t)N * FD * sizeof(__half));
    float*  h1      = (float*)alloc((size_t)N * FD * sizeof(float));
    float*  hsm     = (float*)alloc((size_t)N * FD * sizeof(float));
    float*  Mp      = (float*)alloc((size_t)G * NCH * FD * sizeof(float));
    float*  Sp      = (float*)alloc((size_t)G * NCH * FD * sizeof(float));
    float*  Mm      = (float*)alloc((size_t)G * FD * sizeof(float));
    float*  Sinv    = (float*)alloc((size_t)G * FD * sizeof(float));
    float*  gl      = (float*)alloc((size_t)N * sizeof(float));
    float*  Mg      = (float*)alloc(G * sizeof(float));
    float*  iSg     = (float*)alloc(G * sizeof(float));
    float*  hg      = (float*)alloc((size_t)G * FD * sizeof(float));

    // part[] aliases hw[]: part (E*4B = 6.4MB) is dead after k_fine; hw
    // (N*FD*2B = 12.8MB >= 6.4MB) is first written by k_gemm_al afterwards
    // (stream-ordered).
    unsigned int* part = (unsigned int*)hw;

    int nbN = (N + 255) / 256;   // 196

    // CSR build (two-level partition, no random-address atomics)
    k_zero<<<32, 256, 0, stream>>>(hist, hg);
    k_graph_starts<<<nbN, 256, 0, stream>>>(batch, gs);
    k_hist<<<NBLK_E, 256, 0, stream>>>(dst, hist);
    k_binscan<<<1, 256, 0, stream>>>(hist, binbase, cursor, off);
    k_partition<<<NBLK_E, 256, 0, stream>>>(src, dst, cursor, part);
    k_fine<<<NBIN, 256, 0, stream>>>(part, binbase, off, col);

    auto run_layer = [&](const float* hin, const float* W, const float* a_s,
                         const float* a_d, const float* bias) {
        k_gemm_al<<<(N + 127) / 128, 256, 0, stream>>>(hin, W, a_s, a_d, hw, als, ald);
        k_agg<<<(N + 3) / 4, 256, 0, stream>>>(hw, als, ald, off, col, bias, h1);
        k_colstats_part<<<dim3(G, NCH), 128, 0, stream>>>(h1, gs, Mp, Sp);
        k_colstats_comb<<<G, 128, 0, stream>>>(Mp, Sp, Mm, Sinv);
        k_softmax_gate<<<(N + 3) / 4, 256, 0, stream>>>(h1, batch, Mm, Sinv, gate_w, gate_b, hsm, gl);
        k_gatestats<<<G, 256, 0, stream>>>(gl, gs, Mg, iSg);
        k_pool<<<dim3(G, NCH), 128, 0, stream>>>(hsm, gl, gs, Mg, iSg, hg);
    };

    run_layer(x, W1, as1, ad1, b1);
    run_layer(hsm, W2, as2, ad2, b2);

    k_head<<<G, 64, 0, stream>>>(hg, lin_w, lin_b, cls_w, cls_b, outp);
}